// Round 15
// baseline (115.256 us; speedup 1.0000x reference)
//
#include <hip/hip_runtime.h>
#include <hip/hip_bf16.h>

typedef __attribute__((ext_vector_type(8))) short bf16x8;
typedef __attribute__((ext_vector_type(4))) float f32x4;
typedef __attribute__((ext_vector_type(4))) unsigned u32x4;

#define NEG 0.2f
#define CST 104     // bf16 elems per LDS row (208 B stride)
#define HSTRIDE 11648   // 112*104 bf16 elems per head in d_ws

__device__ __forceinline__ float lrelu(float x) { return x >= 0.0f ? x : NEG * x; }

__device__ __forceinline__ unsigned short f2bf(float x) {
    unsigned u = __builtin_bit_cast(unsigned, x);
    u += 0x7FFFu + ((u >> 16) & 1u);   // RNE
    return (unsigned short)(u >> 16);
}
// packed pair via v_cvt_pk_bf16_f32 (RNE)
__device__ __forceinline__ unsigned pk2(float a, float b) {
    __hip_bfloat162 h = __float22bfloat162_rn(float2{a, b});
    unsigned r;
    __builtin_memcpy(&r, &h, sizeof(r));
    return r;
}

// ---- prep: Wp[h] = [112][104] bf16, exact LDS image ----
// rows 0..99 = W_h[o][f] (cols 100..103 = 0); row 100 = log2e*W_h^T att_src;
// row 101 = log2e*W_h^T att_dst; rows 102..111 = 0.
extern "C" __global__ void prep_w(const float* __restrict__ W,
                                  const float* __restrict__ att_src,
                                  const float* __restrict__ att_dst,
                                  unsigned short* __restrict__ Wp)
{
    const int h = blockIdx.x;      // 4
    const int f = threadIdx.x;     // 0..127
    const float* __restrict__ Wh = W + h * 10000;
    unsigned short* __restrict__ D = Wp + h * HSTRIDE;
    float ws = 0.0f, wd = 0.0f;
    if (f < 100) {
        for (int o = 0; o < 100; ++o) {
            float wv = Wh[o * 100 + f];
            ws = fmaf(att_src[h * 100 + o], wv, ws);
            wd = fmaf(att_dst[h * 100 + o], wv, wd);
        }
    }
    const float L2E = 1.44269504088896340736f;
    ws *= L2E; wd *= L2E;
    if (f < CST) {
        for (int o = 0; o < 100; ++o)
            D[o * CST + f] = (f < 100) ? f2bf(Wh[o * 100 + f]) : (unsigned short)0;
        D[100 * CST + f] = (f < 100) ? f2bf(ws) : (unsigned short)0;
        D[101 * CST + f] = (f < 100) ? f2bf(wd) : (unsigned short)0;
        for (int o = 102; o < 112; ++o) D[o * CST + f] = 0;
    }
}

// One block per t. 512 threads = 8 waves, one 16-row tile per wave (wave 7
// duplicates tile 6, writes suppressed). LDS 47488 B.
// __launch_bounds__(512,4): the ONLY register envelope this kernel family
// fits without scratch (r10/r14 evidence: (512,4)->64 VGPR clean;
// (512,6)->40-reg cap -> 165 MB scratch; (256,3)+extras -> spill).
// LDS: P  [112][104] bf16 @0     : X (until xf hoisted) -> W_h copy per head
//      HT [112][104] bf16 @23296 : H^T[o][j] per head
//      sas[112] @46592, sad[112] @47040 (f32); sas[100..111] = -1e30 kill
// 2 barriers/head. Logits FREE from GEMM-1 tile 6 (B-rows 100/101 = w~):
// lanes lr=4/5 store C-frag f32x4 to sas/sad. PVprep in exp2 domain.
extern "C" __global__ void __launch_bounds__(512, 4)
gat14(const float* __restrict__ A, const unsigned short* __restrict__ Wp,
      const float* __restrict__ bias, float* __restrict__ out)
{
    extern __shared__ char smem[];
    unsigned short* P  = (unsigned short*)smem;
    unsigned short* HT = (unsigned short*)(smem + 23296);
    float* sas  = (float*)(smem + 46592);
    float* sad  = (float*)(smem + 47040);
    float* sOut = (float*)smem;

    const int t    = blockIdx.x;
    const int tid  = threadIdx.x;      // 0..511
    const int w    = tid >> 6;         // 0..7
    const int l    = tid & 63;
    const int lr   = l & 15;
    const int lk   = l >> 4;
    const bool HASW = (w < 7);
    const int row  = HASW ? w : 6;     // wave 7 duplicates tile 6
    const int j0   = row * 16 + 4 * lk;        // 0..108
    const bool JW  = HASW && (j0 < 104);
    const float* __restrict__ At = A + (size_t)t * 10000u;
    const f32x4 z4 = {0, 0, 0, 0};

    // ---- zero P; init sas/sad (sas[100..111] large-negative) ----
    for (int i = tid; i < 1456; i += 512) ((f32x4*)smem)[i] = z4;
    if (tid < 224) {
        float v = (tid >= 100 && tid < 112) ? -1e30f : 0.0f;
        ((float*)(smem + 46592))[tid] = v;
    }
    __syncthreads();

    // ---- stage A_t^T -> P[n][f] bf16 (pk2 pairs along f) ----
#pragma unroll
    for (int k = 0; k < 3; ++k) {
        const int q = tid + k * 512;
        if (q < 1250) {
            const int fp = q / 25, n0 = (q - fp * 25) * 4, f = fp * 2;
            float4 va = *(const float4*)(At + f * 100 + n0);
            float4 vb = *(const float4*)(At + (f + 1) * 100 + n0);
            *(unsigned*)(P + (n0 + 0) * CST + f) = pk2(va.x, vb.x);
            *(unsigned*)(P + (n0 + 1) * CST + f) = pk2(va.y, vb.y);
            *(unsigned*)(P + (n0 + 2) * CST + f) = pk2(va.z, vb.z);
            *(unsigned*)(P + (n0 + 3) * CST + f) = pk2(va.w, vb.w);
        }
    }
    __syncthreads();

    // ---- hoist X fragments ----
    const bf16x8 zf = {0, 0, 0, 0, 0, 0, 0, 0};
    bf16x8 xf[4];
#pragma unroll
    for (int ks = 0; ks < 4; ++ks) {
        const bool kill = (ks == 3) && (lk != 0);
        const int koff = kill ? 96 : ks * 32 + lk * 8;
        bf16x8 v = *(const bf16x8*)(P + (row * 16 + lr) * CST + koff);
        xf[ks] = kill ? zf : v;
    }
    __syncthreads();   // hoist done -> P writable

    f32x4 acc[7];
#pragma unroll
    for (int c = 0; c < 7; ++c) acc[c] = z4;

    for (int h = 0; h < 4; ++h) {
        // ---- Wfill: pure 16B copy of prepped head image into P ----
        {
            const u32x4* __restrict__ Wg = (const u32x4*)(Wp + h * HSTRIDE);
#pragma unroll
            for (int k = 0; k < 3; ++k) {
                const int q = tid + k * 512;
                if (q < 1456) ((u32x4*)P)[q] = Wg[q];
            }
        }
        __syncthreads();   // (b) W ready; also fences prev PV's HT reads

        // ---- GEMM-1, two N-halves; logits free from tile 6 ----
#pragma unroll
        for (int half = 0; half < 2; ++half) {
            const int ntn = half ? 3 : 4;
            f32x4 c[4];
#pragma unroll
            for (int cc = 0; cc < 4; ++cc) c[cc] = z4;
#pragma unroll
            for (int ks = 0; ks < 4; ++ks) {
                const int koff = ks * 32 + lk * 8;   // A-side zero kills k-pad
                bf16x8 b[4];
#pragma unroll
                for (int bb = 0; bb < 4; ++bb)
                    if (bb < ntn)
                        b[bb] = *(const bf16x8*)(P + ((half * 4 + bb) * 16 + lr) * CST + koff);
#pragma unroll
                for (int bb = 0; bb < 4; ++bb)
                    if (bb < ntn)
                        c[bb] = __builtin_amdgcn_mfma_f32_16x16x32_bf16(xf[ks], b[bb], c[bb], 0, 0, 0);
            }
#pragma unroll
            for (int bb = 0; bb < 4; ++bb)
                if (bb < ntn) {
                    const int o = (half * 4 + bb) * 16 + lr;
                    if (JW) {
                        uint2 pp;
                        pp.x = pk2(c[bb].x, c[bb].y);
                        pp.y = pk2(c[bb].z, c[bb].w);
                        *(uint2*)(HT + o * CST + j0) = pp;
                    }
                }
            if (half == 1) {   // tile 6 C-cols 100/101 = a_s', a_d' (log2 domain)
                if (lr == 4 && HASW && j0 < 100) *(f32x4*)(sas + j0) = c[2];
                if (lr == 5 && JW)               *(f32x4*)(sad + j0) = c[2];
            }
        }
        __syncthreads();   // (c) HT + sas/sad ready

        // ---- PVprep: exp2-domain E + row-sum, normalize, pack bf16 ----
        const float adi = sad[row * 16 + lr];
        float ev[32];
        float sE = 0.0f;
#pragma unroll
        for (int ks = 0; ks < 4; ++ks) {
            const bool dead = (ks == 3) && (lk != 0);
            const int jb = dead ? 64 : ks * 32 + lk * 8;
            const f32x4 s0 = *(const f32x4*)(sas + jb);
            const f32x4 s1 = *(const f32x4*)(sas + jb + 4);
            ev[ks * 8 + 0] = dead ? 0.0f : exp2f(lrelu(adi + s0.x));
            ev[ks * 8 + 1] = dead ? 0.0f : exp2f(lrelu(adi + s0.y));
            ev[ks * 8 + 2] = dead ? 0.0f : exp2f(lrelu(adi + s0.z));
            ev[ks * 8 + 3] = dead ? 0.0f : exp2f(lrelu(adi + s0.w));
            ev[ks * 8 + 4] = dead ? 0.0f : exp2f(lrelu(adi + s1.x));
            ev[ks * 8 + 5] = dead ? 0.0f : exp2f(lrelu(adi + s1.y));
            ev[ks * 8 + 6] = dead ? 0.0f : exp2f(lrelu(adi + s1.z));
            ev[ks * 8 + 7] = dead ? 0.0f : exp2f(lrelu(adi + s1.w));
#pragma unroll
            for (int jj = 0; jj < 8; ++jj) sE += ev[ks * 8 + jj];
        }
        sE += __shfl_xor(sE, 16);
        sE += __shfl_xor(sE, 32);
        const float invE = sE > 0.0f ? __builtin_amdgcn_rcpf(sE) : 0.0f;
        bf16x8 af[4];
#pragma unroll
        for (int ks = 0; ks < 4; ++ks) {
            u32x4 uv;
            uv.x = pk2(ev[ks * 8 + 0] * invE, ev[ks * 8 + 1] * invE);
            uv.y = pk2(ev[ks * 8 + 2] * invE, ev[ks * 8 + 3] * invE);
            uv.z = pk2(ev[ks * 8 + 4] * invE, ev[ks * 8 + 5] * invE);
            uv.w = pk2(ev[ks * 8 + 6] * invE, ev[ks * 8 + 7] * invE);
            af[ks] = __builtin_bit_cast(bf16x8, uv);
        }

        // ---- PV: acc += alpha * H (direct C accumulation) ----
#pragma unroll
        for (int half = 0; half < 2; ++half) {
            const int ntn = half ? 3 : 4;
#pragma unroll
            for (int ks = 0; ks < 4; ++ks) {
                const int koff = ks * 32 + lk * 8;
                bf16x8 b[4];
#pragma unroll
                for (int bb = 0; bb < 4; ++bb)
                    if (bb < ntn)
                        b[bb] = *(const bf16x8*)(HT + ((half * 4 + bb) * 16 + lr) * CST + koff);
#pragma unroll
                for (int bb = 0; bb < 4; ++bb)
                    if (bb < ntn)
                        acc[half * 4 + bb] = __builtin_amdgcn_mfma_f32_16x16x32_bf16(
                            af[ks], b[bb], acc[half * 4 + bb], 0, 0, 0);
            }
        }
    }
    __syncthreads();   // all PV done; P+HT dead -> sOut overlay

    // ---- epilogue: sOut[o][i] = lrelu(acc*0.25 + bias[o]) + (i==o) ----
    if (JW) {
        const int i0 = j0;
#pragma unroll
        for (int tn = 0; tn < 7; ++tn) {
            const int o = tn * 16 + lr;
            const float b = (o < 100) ? bias[o] : 0.0f;
            f32x4 v;
            v.x = lrelu(acc[tn].x * 0.25f + b) + ((i0 + 0) == o ? 1.0f : 0.0f);
            v.y = lrelu(acc[tn].y * 0.25f + b) + ((i0 + 1) == o ? 1.0f : 0.0f);
            v.z = lrelu(acc[tn].z * 0.25f + b) + ((i0 + 2) == o ? 1.0f : 0.0f);
            v.w = lrelu(acc[tn].w * 0.25f + b) + ((i0 + 3) == o ? 1.0f : 0.0f);
            *(f32x4*)(sOut + o * 104 + i0) = v;
        }
    }
    __syncthreads();

    // ---- coalesced store out[t][o][i] ----
    float* __restrict__ outT = out + (size_t)t * 10000u;
    for (int q = tid; q < 2500; q += 512) {
        int o = q / 25, i0 = (q - o * 25) * 4;
        *(float4*)(outT + o * 100 + i0) = *(const float4*)(sOut + o * 104 + i0);
    }
}

extern "C" void kernel_launch(void* const* d_in, const int* in_sizes, int n_in,
                              void* d_out, int out_size, void* d_ws, size_t ws_size,
                              hipStream_t stream) {
    const float* A      = (const float*)d_in[0];
    const float* W      = (const float*)d_in[1];
    const float* attsrc = (const float*)d_in[2];
    const float* attdst = (const float*)d_in[3];
    const float* bias   = (const float*)d_in[4];
    float* outp = (float*)d_out;
    unsigned short* Wp = (unsigned short*)d_ws;   // 4*11648*2 = 93184 B

    const int T = in_sizes[0] / 10000;   // 1024

    prep_w<<<4, 128, 0, stream>>>(W, attsrc, attdst, Wp);

    const int smem_bytes = 47488;
    gat14<<<T, 512, smem_bytes, stream>>>(A, Wp, bias, outp);
}

// Round 16
// 108.438 us; speedup vs baseline: 1.0629x; 1.0629x over previous
//
#include <hip/hip_runtime.h>
#include <hip/hip_bf16.h>

typedef __attribute__((ext_vector_type(8))) short bf16x8;
typedef __attribute__((ext_vector_type(4))) float f32x4;
typedef __attribute__((ext_vector_type(4))) unsigned u32x4;

#define NEG 0.2f
#define CST 104     // bf16 elems per LDS row (208 B stride)
#define HSTRIDE 11648   // 112*104 bf16 elems per head in d_ws

__device__ __forceinline__ float lrelu(float x) { return x >= 0.0f ? x : NEG * x; }

__device__ __forceinline__ unsigned short f2bf(float x) {
    unsigned u = __builtin_bit_cast(unsigned, x);
    u += 0x7FFFu + ((u >> 16) & 1u);   // RNE
    return (unsigned short)(u >> 16);
}
// packed pair via v_cvt_pk_bf16_f32 (RNE)
__device__ __forceinline__ unsigned pk2(float a, float b) {
    __hip_bfloat162 h = __float22bfloat162_rn(float2{a, b});
    unsigned r;
    __builtin_memcpy(&r, &h, sizeof(r));
    return r;
}

// ---- prep: Wp[h] = [112][104] bf16, exact LDS image ----
// rows 0..99 = W_h[o][f] (cols 100..103 = 0); row 100 = W_h^T att_src;
// row 101 = W_h^T att_dst; rows 102..111 = 0.  (plain e-domain logits)
extern "C" __global__ void prep_w(const float* __restrict__ W,
                                  const float* __restrict__ att_src,
                                  const float* __restrict__ att_dst,
                                  unsigned short* __restrict__ Wp)
{
    const int h = blockIdx.x;      // 4
    const int f = threadIdx.x;     // 0..127
    const float* __restrict__ Wh = W + h * 10000;
    unsigned short* __restrict__ D = Wp + h * HSTRIDE;
    float ws = 0.0f, wd = 0.0f;
    if (f < 100) {
        for (int o = 0; o < 100; ++o) {
            float wv = Wh[o * 100 + f];
            ws = fmaf(att_src[h * 100 + o], wv, ws);
            wd = fmaf(att_dst[h * 100 + o], wv, wd);
        }
    }
    if (f < CST) {
        for (int o = 0; o < 100; ++o)
            D[o * CST + f] = (f < 100) ? f2bf(Wh[o * 100 + f]) : (unsigned short)0;
        D[100 * CST + f] = (f < 100) ? f2bf(ws) : (unsigned short)0;
        D[101 * CST + f] = (f < 100) ? f2bf(wd) : (unsigned short)0;
        for (int o = 102; o < 112; ++o) D[o * CST + f] = 0;
    }
}

// One block per t. 512 threads = 8 waves, one 16-row tile per wave (wave 7
// duplicates tile 6, writes suppressed). LDS 47488 B.
// __launch_bounds__(512,4) = the only clean register envelope (r10/r14/r15).
// PVprep uses __expf ONLY (bare v_exp_f32): plain exp2f lowers to branchy
// __ocml_exp2_f32 and spilled ev[32] to scratch (r14/r15 WRITE 205/236 MB).
// LDS: P  [112][104] bf16 @0     : X (until xf hoisted) -> W_h copy per head
//      HT [112][104] bf16 @23296 : H^T[o][j] per head
//      sas[112] @46592, sad[112] @47040 (f32); sas[100..111] = -1e30 kill
// 2 barriers/head. Logits FREE from GEMM-1 tile 6 (B-rows 100/101 = w~):
// lanes lr=4/5 store C-frag f32x4 to sas/sad.
extern "C" __global__ void __launch_bounds__(512, 4)
gat15(const float* __restrict__ A, const unsigned short* __restrict__ Wp,
      const float* __restrict__ bias, float* __restrict__ out)
{
    extern __shared__ char smem[];
    unsigned short* P  = (unsigned short*)smem;
    unsigned short* HT = (unsigned short*)(smem + 23296);
    float* sas  = (float*)(smem + 46592);
    float* sad  = (float*)(smem + 47040);
    float* sOut = (float*)smem;

    const int t    = blockIdx.x;
    const int tid  = threadIdx.x;      // 0..511
    const int w    = tid >> 6;         // 0..7
    const int l    = tid & 63;
    const int lr   = l & 15;
    const int lk   = l >> 4;
    const bool HASW = (w < 7);
    const int row  = HASW ? w : 6;     // wave 7 duplicates tile 6
    const int j0   = row * 16 + 4 * lk;        // 0..108
    const bool JW  = HASW && (j0 < 104);
    const float* __restrict__ At = A + (size_t)t * 10000u;
    const f32x4 z4 = {0, 0, 0, 0};

    // ---- zero P; init sas/sad (sas[100..111] large-negative) ----
    for (int i = tid; i < 1456; i += 512) ((f32x4*)smem)[i] = z4;
    if (tid < 224) {
        float v = (tid >= 100 && tid < 112) ? -1e30f : 0.0f;
        ((float*)(smem + 46592))[tid] = v;
    }
    __syncthreads();

    // ---- stage A_t^T -> P[n][f] bf16 (pk2 pairs along f) ----
#pragma unroll
    for (int k = 0; k < 3; ++k) {
        const int q = tid + k * 512;
        if (q < 1250) {
            const int fp = q / 25, n0 = (q - fp * 25) * 4, f = fp * 2;
            float4 va = *(const float4*)(At + f * 100 + n0);
            float4 vb = *(const float4*)(At + (f + 1) * 100 + n0);
            *(unsigned*)(P + (n0 + 0) * CST + f) = pk2(va.x, vb.x);
            *(unsigned*)(P + (n0 + 1) * CST + f) = pk2(va.y, vb.y);
            *(unsigned*)(P + (n0 + 2) * CST + f) = pk2(va.z, vb.z);
            *(unsigned*)(P + (n0 + 3) * CST + f) = pk2(va.w, vb.w);
        }
    }
    __syncthreads();

    // ---- hoist X fragments ----
    const bf16x8 zf = {0, 0, 0, 0, 0, 0, 0, 0};
    bf16x8 xf[4];
#pragma unroll
    for (int ks = 0; ks < 4; ++ks) {
        const bool kill = (ks == 3) && (lk != 0);
        const int koff = kill ? 96 : ks * 32 + lk * 8;
        bf16x8 v = *(const bf16x8*)(P + (row * 16 + lr) * CST + koff);
        xf[ks] = kill ? zf : v;
    }
    __syncthreads();   // hoist done -> P writable

    f32x4 acc[7];
#pragma unroll
    for (int c = 0; c < 7; ++c) acc[c] = z4;

    for (int h = 0; h < 4; ++h) {
        // ---- Wfill: pure 16B copy of prepped head image into P ----
        {
            const u32x4* __restrict__ Wg = (const u32x4*)(Wp + h * HSTRIDE);
#pragma unroll
            for (int k = 0; k < 3; ++k) {
                const int q = tid + k * 512;
                if (q < 1456) ((u32x4*)P)[q] = Wg[q];
            }
        }
        __syncthreads();   // (b) W ready; also fences prev PV's HT reads

        // ---- GEMM-1, two N-halves; logits free from tile 6 ----
#pragma unroll
        for (int half = 0; half < 2; ++half) {
            const int ntn = half ? 3 : 4;
            f32x4 c[4];
#pragma unroll
            for (int cc = 0; cc < 4; ++cc) c[cc] = z4;
#pragma unroll
            for (int ks = 0; ks < 4; ++ks) {
                const int koff = ks * 32 + lk * 8;   // A-side zero kills k-pad
                bf16x8 b[4];
#pragma unroll
                for (int bb = 0; bb < 4; ++bb)
                    if (bb < ntn)
                        b[bb] = *(const bf16x8*)(P + ((half * 4 + bb) * 16 + lr) * CST + koff);
#pragma unroll
                for (int bb = 0; bb < 4; ++bb)
                    if (bb < ntn)
                        c[bb] = __builtin_amdgcn_mfma_f32_16x16x32_bf16(xf[ks], b[bb], c[bb], 0, 0, 0);
            }
#pragma unroll
            for (int bb = 0; bb < 4; ++bb)
                if (bb < ntn) {
                    const int o = (half * 4 + bb) * 16 + lr;
                    if (JW) {
                        uint2 pp;
                        pp.x = pk2(c[bb].x, c[bb].y);
                        pp.y = pk2(c[bb].z, c[bb].w);
                        *(uint2*)(HT + o * CST + j0) = pp;
                    }
                }
            if (half == 1) {   // tile 6 C-cols 100/101 = a_s, a_d
                if (lr == 4 && HASW && j0 < 100) *(f32x4*)(sas + j0) = c[2];
                if (lr == 5 && JW)               *(f32x4*)(sad + j0) = c[2];
            }
        }
        __syncthreads();   // (c) HT + sas/sad ready

        // ---- PVprep: __expf E + row-sum, normalize, pack bf16 (r10 path) ----
        const float adi = sad[row * 16 + lr];
        float ev[32];
        float sE = 0.0f;
#pragma unroll
        for (int ks = 0; ks < 4; ++ks) {
            const bool dead = (ks == 3) && (lk != 0);
            const int jb = dead ? 64 : ks * 32 + lk * 8;
            const f32x4 s0 = *(const f32x4*)(sas + jb);
            const f32x4 s1 = *(const f32x4*)(sas + jb + 4);
            ev[ks * 8 + 0] = dead ? 0.0f : __expf(lrelu(adi + s0.x));
            ev[ks * 8 + 1] = dead ? 0.0f : __expf(lrelu(adi + s0.y));
            ev[ks * 8 + 2] = dead ? 0.0f : __expf(lrelu(adi + s0.z));
            ev[ks * 8 + 3] = dead ? 0.0f : __expf(lrelu(adi + s0.w));
            ev[ks * 8 + 4] = dead ? 0.0f : __expf(lrelu(adi + s1.x));
            ev[ks * 8 + 5] = dead ? 0.0f : __expf(lrelu(adi + s1.y));
            ev[ks * 8 + 6] = dead ? 0.0f : __expf(lrelu(adi + s1.z));
            ev[ks * 8 + 7] = dead ? 0.0f : __expf(lrelu(adi + s1.w));
#pragma unroll
            for (int jj = 0; jj < 8; ++jj) sE += ev[ks * 8 + jj];
        }
        sE += __shfl_xor(sE, 16);
        sE += __shfl_xor(sE, 32);
        const float invE = sE > 0.0f ? __builtin_amdgcn_rcpf(sE) : 0.0f;
        bf16x8 af[4];
#pragma unroll
        for (int ks = 0; ks < 4; ++ks) {
            u32x4 uv;
            uv.x = pk2(ev[ks * 8 + 0] * invE, ev[ks * 8 + 1] * invE);
            uv.y = pk2(ev[ks * 8 + 2] * invE, ev[ks * 8 + 3] * invE);
            uv.z = pk2(ev[ks * 8 + 4] * invE, ev[ks * 8 + 5] * invE);
            uv.w = pk2(ev[ks * 8 + 6] * invE, ev[ks * 8 + 7] * invE);
            af[ks] = __builtin_bit_cast(bf16x8, uv);
        }

        // ---- PV: acc += alpha * H (direct C accumulation) ----
#pragma unroll
        for (int half = 0; half < 2; ++half) {
            const int ntn = half ? 3 : 4;
#pragma unroll
            for (int ks = 0; ks < 4; ++ks) {
                const int koff = ks * 32 + lk * 8;
                bf16x8 b[4];
#pragma unroll
                for (int bb = 0; bb < 4; ++bb)
                    if (bb < ntn)
                        b[bb] = *(const bf16x8*)(HT + ((half * 4 + bb) * 16 + lr) * CST + koff);
#pragma unroll
                for (int bb = 0; bb < 4; ++bb)
                    if (bb < ntn)
                        acc[half * 4 + bb] = __builtin_amdgcn_mfma_f32_16x16x32_bf16(
                            af[ks], b[bb], acc[half * 4 + bb], 0, 0, 0);
            }
        }
    }
    __syncthreads();   // all PV done; P+HT dead -> sOut overlay

    // ---- epilogue: sOut[o][i] = lrelu(acc*0.25 + bias[o]) + (i==o) ----
    if (JW) {
        const int i0 = j0;
#pragma unroll
        for (int tn = 0; tn < 7; ++tn) {
            const int o = tn * 16 + lr;
            const float b = (o < 100) ? bias[o] : 0.0f;
            f32x4 v;
            v.x = lrelu(acc[tn].x * 0.25f + b) + ((i0 + 0) == o ? 1.0f : 0.0f);
            v.y = lrelu(acc[tn].y * 0.25f + b) + ((i0 + 1) == o ? 1.0f : 0.0f);
            v.z = lrelu(acc[tn].z * 0.25f + b) + ((i0 + 2) == o ? 1.0f : 0.0f);
            v.w = lrelu(acc[tn].w * 0.25f + b) + ((i0 + 3) == o ? 1.0f : 0.0f);
            *(f32x4*)(sOut + o * 104 + i0) = v;
        }
    }
    __syncthreads();

    // ---- coalesced store out[t][o][i] ----
    float* __restrict__ outT = out + (size_t)t * 10000u;
    for (int q = tid; q < 2500; q += 512) {
        int o = q / 25, i0 = (q - o * 25) * 4;
        *(float4*)(outT + o * 100 + i0) = *(const float4*)(sOut + o * 104 + i0);
    }
}

extern "C" void kernel_launch(void* const* d_in, const int* in_sizes, int n_in,
                              void* d_out, int out_size, void* d_ws, size_t ws_size,
                              hipStream_t stream) {
    const float* A      = (const float*)d_in[0];
    const float* W      = (const float*)d_in[1];
    const float* attsrc = (const float*)d_in[2];
    const float* attdst = (const float*)d_in[3];
    const float* bias   = (const float*)d_in[4];
    float* outp = (float*)d_out;
    unsigned short* Wp = (unsigned short*)d_ws;   // 4*11648*2 = 93184 B

    const int T = in_sizes[0] / 10000;   // 1024

    prep_w<<<4, 128, 0, stream>>>(W, attsrc, attdst, Wp);

    const int smem_bytes = 47488;
    gat15<<<T, 512, smem_bytes, stream>>>(A, Wp, bias, outp);
}

// Round 17
// 80.048 us; speedup vs baseline: 1.4398x; 1.3547x over previous
//
#include <hip/hip_runtime.h>
#include <hip/hip_bf16.h>

typedef __attribute__((ext_vector_type(8))) short bf16x8;
typedef __attribute__((ext_vector_type(4))) float f32x4;
typedef __attribute__((ext_vector_type(4))) unsigned u32x4;

#define NEG 0.2f
#define CST 104     // bf16 elems per LDS row (208 B stride)
#define HSTRIDE 11648   // 112*104 bf16 elems per head in d_ws

__device__ __forceinline__ float lrelu(float x) { return x >= 0.0f ? x : NEG * x; }

__device__ __forceinline__ unsigned short f2bf(float x) {
    unsigned u = __builtin_bit_cast(unsigned, x);
    u += 0x7FFFu + ((u >> 16) & 1u);   // RNE
    return (unsigned short)(u >> 16);
}
// packed pair via v_cvt_pk_bf16_f32 (RNE)
__device__ __forceinline__ unsigned pk2(float a, float b) {
    __hip_bfloat162 h = __float22bfloat162_rn(float2{a, b});
    unsigned r;
    __builtin_memcpy(&r, &h, sizeof(r));
    return r;
}
__device__ __forceinline__ float bflo(unsigned u) {
    unsigned v = u << 16; float f; __builtin_memcpy(&f, &v, 4); return f;
}
__device__ __forceinline__ float bfhi(unsigned u) {
    unsigned v = u & 0xffff0000u; float f; __builtin_memcpy(&f, &v, 4); return f;
}

// ---- prep: Wp[h] = [112][104] bf16, exact LDS image ----
// rows 0..99 = W_h[o][f] (cols 100..103 = 0); row 100 = W_h^T att_src;
// row 101 = W_h^T att_dst; rows 102..111 = 0.
extern "C" __global__ void prep_w(const float* __restrict__ W,
                                  const float* __restrict__ att_src,
                                  const float* __restrict__ att_dst,
                                  unsigned short* __restrict__ Wp)
{
    const int h = blockIdx.x;      // 4
    const int f = threadIdx.x;     // 0..127
    const float* __restrict__ Wh = W + h * 10000;
    unsigned short* __restrict__ D = Wp + h * HSTRIDE;
    float ws = 0.0f, wd = 0.0f;
    if (f < 100) {
        for (int o = 0; o < 100; ++o) {
            float wv = Wh[o * 100 + f];
            ws = fmaf(att_src[h * 100 + o], wv, ws);
            wd = fmaf(att_dst[h * 100 + o], wv, wd);
        }
    }
    if (f < CST) {
        for (int o = 0; o < 100; ++o)
            D[o * CST + f] = (f < 100) ? f2bf(Wh[o * 100 + f]) : (unsigned short)0;
        D[100 * CST + f] = (f < 100) ? f2bf(ws) : (unsigned short)0;
        D[101 * CST + f] = (f < 100) ? f2bf(wd) : (unsigned short)0;
        for (int o = 102; o < 112; ++o) D[o * CST + f] = 0;
    }
}

// One block per t. 512 threads = 8 waves, one 16-row tile per wave (wave 7
// duplicates tile 6, writes suppressed). LDS 47488 B. __launch_bounds__(512,4).
// PVprep is LOW-PRESSURE: per-ks 8 transient f32 exps -> unnormalized bf16
// af[ks] immediately (no ev[32] array), then bf16-domain rescale by 1/sum.
// This removes the ~20-reg live peak that spilled r13-r16 (WRITE 200+ MB).
// LDS: P  [112][104] bf16 @0     : X (until xf hoisted) -> W_h copy per head
//      HT [112][104] bf16 @23296 : H^T[o][j] per head
//      sas[112] @46592, sad[112] @47040 (f32); sas[100..111] = -1e30 kill
// 2 barriers/head. Logits FREE from GEMM-1 tile 6 (B-rows 100/101 = w~).
extern "C" __global__ void __launch_bounds__(512, 4)
gat16(const float* __restrict__ A, const unsigned short* __restrict__ Wp,
      const float* __restrict__ bias, float* __restrict__ out)
{
    extern __shared__ char smem[];
    unsigned short* P  = (unsigned short*)smem;
    unsigned short* HT = (unsigned short*)(smem + 23296);
    float* sas  = (float*)(smem + 46592);
    float* sad  = (float*)(smem + 47040);
    float* sOut = (float*)smem;

    const int t    = blockIdx.x;
    const int tid  = threadIdx.x;      // 0..511
    const int w    = tid >> 6;         // 0..7
    const int l    = tid & 63;
    const int lr   = l & 15;
    const int lk   = l >> 4;
    const bool HASW = (w < 7);
    const int row  = HASW ? w : 6;     // wave 7 duplicates tile 6
    const int j0   = row * 16 + 4 * lk;        // 0..108
    const bool JW  = HASW && (j0 < 104);
    const float* __restrict__ At = A + (size_t)t * 10000u;
    const f32x4 z4 = {0, 0, 0, 0};

    // ---- zero P; init sas/sad (sas[100..111] large-negative) ----
    for (int i = tid; i < 1456; i += 512) ((f32x4*)smem)[i] = z4;
    if (tid < 224) {
        float v = (tid >= 100 && tid < 112) ? -1e30f : 0.0f;
        ((float*)(smem + 46592))[tid] = v;
    }
    __syncthreads();

    // ---- stage A_t^T -> P[n][f] bf16 (pk2 pairs along f) ----
#pragma unroll
    for (int k = 0; k < 3; ++k) {
        const int q = tid + k * 512;
        if (q < 1250) {
            const int fp = q / 25, n0 = (q - fp * 25) * 4, f = fp * 2;
            float4 va = *(const float4*)(At + f * 100 + n0);
            float4 vb = *(const float4*)(At + (f + 1) * 100 + n0);
            *(unsigned*)(P + (n0 + 0) * CST + f) = pk2(va.x, vb.x);
            *(unsigned*)(P + (n0 + 1) * CST + f) = pk2(va.y, vb.y);
            *(unsigned*)(P + (n0 + 2) * CST + f) = pk2(va.z, vb.z);
            *(unsigned*)(P + (n0 + 3) * CST + f) = pk2(va.w, vb.w);
        }
    }
    __syncthreads();

    // ---- hoist X fragments ----
    const bf16x8 zf = {0, 0, 0, 0, 0, 0, 0, 0};
    bf16x8 xf[4];
#pragma unroll
    for (int ks = 0; ks < 4; ++ks) {
        const bool kill = (ks == 3) && (lk != 0);
        const int koff = kill ? 96 : ks * 32 + lk * 8;
        bf16x8 v = *(const bf16x8*)(P + (row * 16 + lr) * CST + koff);
        xf[ks] = kill ? zf : v;
    }
    __syncthreads();   // hoist done -> P writable

    f32x4 acc[7];
#pragma unroll
    for (int c = 0; c < 7; ++c) acc[c] = z4;

    for (int h = 0; h < 4; ++h) {
        // ---- Wfill: pure 16B copy of prepped head image into P ----
        {
            const u32x4* __restrict__ Wg = (const u32x4*)(Wp + h * HSTRIDE);
#pragma unroll
            for (int k = 0; k < 3; ++k) {
                const int q = tid + k * 512;
                if (q < 1456) ((u32x4*)P)[q] = Wg[q];
            }
        }
        __syncthreads();   // (b) W ready; also fences prev PV's HT reads

        // ---- GEMM-1, two N-halves; logits free from tile 6 ----
#pragma unroll
        for (int half = 0; half < 2; ++half) {
            const int ntn = half ? 3 : 4;
            f32x4 c[4];
#pragma unroll
            for (int cc = 0; cc < 4; ++cc) c[cc] = z4;
#pragma unroll
            for (int ks = 0; ks < 4; ++ks) {
                const int koff = ks * 32 + lk * 8;   // A-side zero kills k-pad
                bf16x8 b[4];
#pragma unroll
                for (int bb = 0; bb < 4; ++bb)
                    if (bb < ntn)
                        b[bb] = *(const bf16x8*)(P + ((half * 4 + bb) * 16 + lr) * CST + koff);
#pragma unroll
                for (int bb = 0; bb < 4; ++bb)
                    if (bb < ntn)
                        c[bb] = __builtin_amdgcn_mfma_f32_16x16x32_bf16(xf[ks], b[bb], c[bb], 0, 0, 0);
            }
#pragma unroll
            for (int bb = 0; bb < 4; ++bb)
                if (bb < ntn) {
                    const int o = (half * 4 + bb) * 16 + lr;
                    if (JW) {
                        uint2 pp;
                        pp.x = pk2(c[bb].x, c[bb].y);
                        pp.y = pk2(c[bb].z, c[bb].w);
                        *(uint2*)(HT + o * CST + j0) = pp;
                    }
                }
            if (half == 1) {   // tile 6 C-cols 100/101 = a_s, a_d
                if (lr == 4 && HASW && j0 < 100) *(f32x4*)(sas + j0) = c[2];
                if (lr == 5 && JW)               *(f32x4*)(sad + j0) = c[2];
            }
        }
        __syncthreads();   // (c) HT + sas/sad ready

        // ---- PVprep: per-ks transient exps -> unnormalized bf16 af; f32 sum ----
        const float adi = sad[row * 16 + lr];
        float sE = 0.0f;
        bf16x8 af[4];
#pragma unroll
        for (int ks = 0; ks < 4; ++ks) {
            const bool dead = (ks == 3) && (lk != 0);
            const int jb = dead ? 64 : ks * 32 + lk * 8;
            const f32x4 s0 = *(const f32x4*)(sas + jb);
            const f32x4 s1 = *(const f32x4*)(sas + jb + 4);
            float e0 = dead ? 0.0f : __expf(lrelu(adi + s0.x));
            float e1 = dead ? 0.0f : __expf(lrelu(adi + s0.y));
            float e2 = dead ? 0.0f : __expf(lrelu(adi + s0.z));
            float e3 = dead ? 0.0f : __expf(lrelu(adi + s0.w));
            float e4 = dead ? 0.0f : __expf(lrelu(adi + s1.x));
            float e5 = dead ? 0.0f : __expf(lrelu(adi + s1.y));
            float e6 = dead ? 0.0f : __expf(lrelu(adi + s1.z));
            float e7 = dead ? 0.0f : __expf(lrelu(adi + s1.w));
            sE += ((e0 + e1) + (e2 + e3)) + ((e4 + e5) + (e6 + e7));
            u32x4 uv;
            uv.x = pk2(e0, e1); uv.y = pk2(e2, e3);
            uv.z = pk2(e4, e5); uv.w = pk2(e6, e7);
            af[ks] = __builtin_bit_cast(bf16x8, uv);
        }
        sE += __shfl_xor(sE, 16);
        sE += __shfl_xor(sE, 32);
        const float invE = sE > 0.0f ? __builtin_amdgcn_rcpf(sE) : 0.0f;
#pragma unroll
        for (int ks = 0; ks < 4; ++ks) {   // bf16-domain rescale (low pressure)
            u32x4 uv = __builtin_bit_cast(u32x4, af[ks]);
            uv.x = pk2(bflo(uv.x) * invE, bfhi(uv.x) * invE);
            uv.y = pk2(bflo(uv.y) * invE, bfhi(uv.y) * invE);
            uv.z = pk2(bflo(uv.z) * invE, bfhi(uv.z) * invE);
            uv.w = pk2(bflo(uv.w) * invE, bfhi(uv.w) * invE);
            af[ks] = __builtin_bit_cast(bf16x8, uv);
        }

        // ---- PV: acc += alpha * H (direct C accumulation) ----
#pragma unroll
        for (int half = 0; half < 2; ++half) {
            const int ntn = half ? 3 : 4;
#pragma unroll
            for (int ks = 0; ks < 4; ++ks) {
                const int koff = ks * 32 + lk * 8;
                bf16x8 b[4];
#pragma unroll
                for (int bb = 0; bb < 4; ++bb)
                    if (bb < ntn)
                        b[bb] = *(const bf16x8*)(HT + ((half * 4 + bb) * 16 + lr) * CST + koff);
#pragma unroll
                for (int bb = 0; bb < 4; ++bb)
                    if (bb < ntn)
                        acc[half * 4 + bb] = __builtin_amdgcn_mfma_f32_16x16x32_bf16(
                            af[ks], b[bb], acc[half * 4 + bb], 0, 0, 0);
            }
        }
    }
    __syncthreads();   // all PV done; P+HT dead -> sOut overlay

    // ---- epilogue: sOut[o][i] = lrelu(acc*0.25 + bias[o]) + (i==o) ----
    if (JW) {
        const int i0 = j0;
#pragma unroll
        for (int tn = 0; tn < 7; ++tn) {
            const int o = tn * 16 + lr;
            const float b = (o < 100) ? bias[o] : 0.0f;
            f32x4 v;
            v.x = lrelu(acc[tn].x * 0.25f + b) + ((i0 + 0) == o ? 1.0f : 0.0f);
            v.y = lrelu(acc[tn].y * 0.25f + b) + ((i0 + 1) == o ? 1.0f : 0.0f);
            v.z = lrelu(acc[tn].z * 0.25f + b) + ((i0 + 2) == o ? 1.0f : 0.0f);
            v.w = lrelu(acc[tn].w * 0.25f + b) + ((i0 + 3) == o ? 1.0f : 0.0f);
            *(f32x4*)(sOut + o * 104 + i0) = v;
        }
    }
    __syncthreads();

    // ---- coalesced store out[t][o][i] ----
    float* __restrict__ outT = out + (size_t)t * 10000u;
    for (int q = tid; q < 2500; q += 512) {
        int o = q / 25, i0 = (q - o * 25) * 4;
        *(float4*)(outT + o * 100 + i0) = *(const float4*)(sOut + o * 104 + i0);
    }
}

extern "C" void kernel_launch(void* const* d_in, const int* in_sizes, int n_in,
                              void* d_out, int out_size, void* d_ws, size_t ws_size,
                              hipStream_t stream) {
    const float* A      = (const float*)d_in[0];
    const float* W      = (const float*)d_in[1];
    const float* attsrc = (const float*)d_in[2];
    const float* attdst = (const float*)d_in[3];
    const float* bias   = (const float*)d_in[4];
    float* outp = (float*)d_out;
    unsigned short* Wp = (unsigned short*)d_ws;   // 4*11648*2 = 93184 B

    const int T = in_sizes[0] / 10000;   // 1024

    prep_w<<<4, 128, 0, stream>>>(W, attsrc, attdst, Wp);

    const int smem_bytes = 47488;
    gat16<<<T, 512, smem_bytes, stream>>>(A, Wp, bias, outp);
}

// Round 18
// 68.136 us; speedup vs baseline: 1.6915x; 1.1748x over previous
//
#include <hip/hip_runtime.h>
#include <hip/hip_bf16.h>

typedef __attribute__((ext_vector_type(8))) short bf16x8;
typedef __attribute__((ext_vector_type(4))) float f32x4;
typedef __attribute__((ext_vector_type(4))) unsigned u32x4;

#define NEG 0.2f
#define CST 104     // bf16 elems per LDS row (208 B stride)
#define HSTRIDE 11648   // 112*104 bf16 elems per head in d_ws

__device__ __forceinline__ float lrelu(float x) { return x >= 0.0f ? x : NEG * x; }

// packed pair via v_cvt_pk_bf16_f32 (RNE)
__device__ __forceinline__ unsigned pk2(float a, float b) {
    __hip_bfloat162 h = __float22bfloat162_rn(float2{a, b});
    unsigned r;
    __builtin_memcpy(&r, &h, sizeof(r));
    return r;
}
__device__ __forceinline__ float bflo(unsigned u) {
    unsigned v = u << 16; float f; __builtin_memcpy(&f, &v, 4); return f;
}
__device__ __forceinline__ float bfhi(unsigned u) {
    unsigned v = u & 0xffff0000u; float f; __builtin_memcpy(&f, &v, 4); return f;
}

// ---- prep (fast): Wp[h] = [112][104] bf16, exact LDS image ----
// rows 0..99 = W_h[o][f]; row 100 = W_h^T att_src; row 101 = W_h^T att_dst;
// all pads zero. 4 blocks x 512 threads: 4-way split o-partials + LDS reduce.
extern "C" __global__ void prep_w(const float* __restrict__ W,
                                  const float* __restrict__ att_src,
                                  const float* __restrict__ att_dst,
                                  unsigned short* __restrict__ Wp)
{
    __shared__ float red[2][4][128];
    __shared__ float sWS[128], sWD[128];
    const int h = blockIdx.x, tid = threadIdx.x;
    const int f = tid & 127, og = tid >> 7;   // og 0..3 -> o in [og*25, og*25+25)
    const float* __restrict__ Wh = W + h * 10000;
    float ws = 0.0f, wd = 0.0f;
    if (f < 100) {
        for (int o = og * 25; o < og * 25 + 25; ++o) {
            float wv = Wh[o * 100 + f];
            ws = fmaf(att_src[h * 100 + o], wv, ws);
            wd = fmaf(att_dst[h * 100 + o], wv, wd);
        }
    }
    red[0][og][f] = ws;
    red[1][og][f] = wd;
    __syncthreads();
    if (tid < 256) {
        const int which = tid >> 7, ff = tid & 127;
        float s = (red[which][0][ff] + red[which][1][ff]) +
                  (red[which][2][ff] + red[which][3][ff]);
        (which ? sWD : sWS)[ff] = s;
    }
    __syncthreads();
    unsigned short* __restrict__ D = Wp + h * HSTRIDE;
    for (int q = tid; q < 2912; q += 512) {
        const int o = q / 26, f0 = (q - o * 26) * 4;
        uint2 pp = {0u, 0u};
        if (f0 < 100) {          // f0 <= 96 -> f0+3 <= 99 valid
            if (o < 100) {
                float4 wv = *(const float4*)(Wh + o * 100 + f0);
                pp.x = pk2(wv.x, wv.y);
                pp.y = pk2(wv.z, wv.w);
            } else if (o == 100) {
                pp.x = pk2(sWS[f0], sWS[f0 + 1]);
                pp.y = pk2(sWS[f0 + 2], sWS[f0 + 3]);
            } else if (o == 101) {
                pp.x = pk2(sWD[f0], sWD[f0 + 1]);
                pp.y = pk2(sWD[f0 + 2], sWD[f0 + 3]);
            }
        }
        *(uint2*)(D + o * CST + f0) = pp;
    }
}

// One block per t. 512 threads = 8 waves, one 16-row tile per wave (wave 7
// duplicates tile 6, writes suppressed). LDS 47488 B. __launch_bounds__(512,4)
// (the only clean register envelope — r10..r17 evidence).
// X fragments loaded DIRECTLY from global (no LDS staging: deletes the
// 12-way-conflict transpose scatter, the P zero-init, and 2 barriers).
// LDS: P  [112][104] bf16 @0     : W_h copy per head (Wp image, pads baked)
//      HT [112][104] bf16 @23296 : H^T[o][j] per head
//      sas[112] @46592, sad[112] @47040 (f32); sas[100..111] = -1e30 kill
// 2 barriers/head. Logits FREE from GEMM-1 tile 6 (B-rows 100/101 = w~).
// PVprep: per-ks transient exps -> unnormalized bf16 af, bf16-domain rescale
// (low pressure — the r17 fix).
extern "C" __global__ void __launch_bounds__(512, 4)
gat17(const float* __restrict__ A, const unsigned short* __restrict__ Wp,
      const float* __restrict__ bias, float* __restrict__ out)
{
    extern __shared__ char smem[];
    unsigned short* P  = (unsigned short*)smem;
    unsigned short* HT = (unsigned short*)(smem + 23296);
    float* sas  = (float*)(smem + 46592);
    float* sad  = (float*)(smem + 47040);
    float* sOut = (float*)smem;

    const int t    = blockIdx.x;
    const int tid  = threadIdx.x;      // 0..511
    const int w    = tid >> 6;         // 0..7
    const int l    = tid & 63;
    const int lr   = l & 15;
    const int lk   = l >> 4;
    const bool HASW = (w < 7);
    const int row  = HASW ? w : 6;     // wave 7 duplicates tile 6
    const int j0   = row * 16 + 4 * lk;        // 0..108
    const bool JW  = HASW && (j0 < 104);
    const float* __restrict__ At = A + (size_t)t * 10000u;
    const f32x4 z4 = {0, 0, 0, 0};

    // ---- init: sas/sad (sas[100..111] = -1e30); zero HT head (64 B guard) ----
    if (tid < 224) {
        float v = (tid >= 100 && tid < 112) ? -1e30f : 0.0f;
        ((float*)(smem + 46592))[tid] = v;
    }
    if (tid >= 224 && tid < 240) ((unsigned*)(smem + 23296))[tid - 224] = 0;

    // ---- xf: direct global loads of X = A_t^T fragments (no staging) ----
    const int col = row * 16 + lr;     // X row index = A column
    const bool cOK = col < 100;
    bf16x8 xf[4];
#pragma unroll
    for (int ks = 0; ks < 4; ++ks) {
        const bool kill = (ks == 3) && (lk != 0);
        const int koff = ks * 32 + lk * 8;
        u32x4 uv = {0u, 0u, 0u, 0u};
        if (cOK && !kill) {
#pragma unroll
            for (int jp = 0; jp < 4; ++jp) {
                const int f0 = koff + jp * 2;
                float a0 = (f0     < 100) ? At[f0 * 100 + col]       : 0.0f;
                float a1 = (f0 + 1 < 100) ? At[(f0 + 1) * 100 + col] : 0.0f;
                uv[jp] = pk2(a0, a1);
            }
        }
        xf[ks] = __builtin_bit_cast(bf16x8, uv);
    }
    __syncthreads();   // sas/sad + HT-head init visible

    f32x4 acc[7];
#pragma unroll
    for (int c = 0; c < 7; ++c) acc[c] = z4;

    for (int h = 0; h < 4; ++h) {
        // ---- Wfill: pure 16B copy of prepped head image into P ----
        {
            const u32x4* __restrict__ Wg = (const u32x4*)(Wp + h * HSTRIDE);
#pragma unroll
            for (int k = 0; k < 3; ++k) {
                const int q = tid + k * 512;
                if (q < 1456) ((u32x4*)P)[q] = Wg[q];
            }
        }
        __syncthreads();   // (b) W ready; also fences prev PV's HT reads

        // ---- GEMM-1, two N-halves; logits free from tile 6 ----
#pragma unroll
        for (int half = 0; half < 2; ++half) {
            const int ntn = half ? 3 : 4;
            f32x4 c[4];
#pragma unroll
            for (int cc = 0; cc < 4; ++cc) c[cc] = z4;
#pragma unroll
            for (int ks = 0; ks < 4; ++ks) {
                const int koff = ks * 32 + lk * 8;   // A-side zero kills k-pad
                bf16x8 b[4];
#pragma unroll
                for (int bb = 0; bb < 4; ++bb)
                    if (bb < ntn)
                        b[bb] = *(const bf16x8*)(P + ((half * 4 + bb) * 16 + lr) * CST + koff);
#pragma unroll
                for (int bb = 0; bb < 4; ++bb)
                    if (bb < ntn)
                        c[bb] = __builtin_amdgcn_mfma_f32_16x16x32_bf16(xf[ks], b[bb], c[bb], 0, 0, 0);
            }
#pragma unroll
            for (int bb = 0; bb < 4; ++bb)
                if (bb < ntn) {
                    const int o = (half * 4 + bb) * 16 + lr;
                    if (JW) {
                        uint2 pp;
                        pp.x = pk2(c[bb].x, c[bb].y);
                        pp.y = pk2(c[bb].z, c[bb].w);
                        *(uint2*)(HT + o * CST + j0) = pp;
                    }
                }
            if (half == 1) {   // tile 6 C-cols 100/101 = a_s, a_d
                if (lr == 4 && HASW && j0 < 100) *(f32x4*)(sas + j0) = c[2];
                if (lr == 5 && JW)               *(f32x4*)(sad + j0) = c[2];
            }
        }
        __syncthreads();   // (c) HT + sas/sad ready

        // ---- PVprep: per-ks transient exps -> unnorm bf16 af; f32 sum ----
        const float adi = sad[row * 16 + lr];
        float sE = 0.0f;
        bf16x8 af[4];
#pragma unroll
        for (int ks = 0; ks < 4; ++ks) {
            const bool dead = (ks == 3) && (lk != 0);
            const int jb = dead ? 64 : ks * 32 + lk * 8;
            const f32x4 s0 = *(const f32x4*)(sas + jb);
            const f32x4 s1 = *(const f32x4*)(sas + jb + 4);
            float e0 = dead ? 0.0f : __expf(lrelu(adi + s0.x));
            float e1 = dead ? 0.0f : __expf(lrelu(adi + s0.y));
            float e2 = dead ? 0.0f : __expf(lrelu(adi + s0.z));
            float e3 = dead ? 0.0f : __expf(lrelu(adi + s0.w));
            float e4 = dead ? 0.0f : __expf(lrelu(adi + s1.x));
            float e5 = dead ? 0.0f : __expf(lrelu(adi + s1.y));
            float e6 = dead ? 0.0f : __expf(lrelu(adi + s1.z));
            float e7 = dead ? 0.0f : __expf(lrelu(adi + s1.w));
            sE += ((e0 + e1) + (e2 + e3)) + ((e4 + e5) + (e6 + e7));
            u32x4 uv;
            uv.x = pk2(e0, e1); uv.y = pk2(e2, e3);
            uv.z = pk2(e4, e5); uv.w = pk2(e6, e7);
            af[ks] = __builtin_bit_cast(bf16x8, uv);
        }
        sE += __shfl_xor(sE, 16);
        sE += __shfl_xor(sE, 32);
        const float invE = sE > 0.0f ? __builtin_amdgcn_rcpf(sE) : 0.0f;
#pragma unroll
        for (int ks = 0; ks < 4; ++ks) {   // bf16-domain rescale (low pressure)
            u32x4 uv = __builtin_bit_cast(u32x4, af[ks]);
            uv.x = pk2(bflo(uv.x) * invE, bfhi(uv.x) * invE);
            uv.y = pk2(bflo(uv.y) * invE, bfhi(uv.y) * invE);
            uv.z = pk2(bflo(uv.z) * invE, bfhi(uv.z) * invE);
            uv.w = pk2(bflo(uv.w) * invE, bfhi(uv.w) * invE);
            af[ks] = __builtin_bit_cast(bf16x8, uv);
        }

        // ---- PV: acc += alpha * H (direct C accumulation) ----
#pragma unroll
        for (int half = 0; half < 2; ++half) {
            const int ntn = half ? 3 : 4;
#pragma unroll
            for (int ks = 0; ks < 4; ++ks) {
                const int koff = ks * 32 + lk * 8;
                bf16x8 b[4];
#pragma unroll
                for (int bb = 0; bb < 4; ++bb)
                    if (bb < ntn)
                        b[bb] = *(const bf16x8*)(HT + ((half * 4 + bb) * 16 + lr) * CST + koff);
#pragma unroll
                for (int bb = 0; bb < 4; ++bb)
                    if (bb < ntn)
                        acc[half * 4 + bb] = __builtin_amdgcn_mfma_f32_16x16x32_bf16(
                            af[ks], b[bb], acc[half * 4 + bb], 0, 0, 0);
            }
        }
    }
    __syncthreads();   // all PV done; P+HT dead -> sOut overlay

    // ---- epilogue: sOut[o][i] = lrelu(acc*0.25 + bias[o]) + (i==o) ----
    if (JW) {
        const int i0 = j0;
#pragma unroll
        for (int tn = 0; tn < 7; ++tn) {
            const int o = tn * 16 + lr;
            const float b = (o < 100) ? bias[o] : 0.0f;
            f32x4 v;
            v.x = lrelu(acc[tn].x * 0.25f + b) + ((i0 + 0) == o ? 1.0f : 0.0f);
            v.y = lrelu(acc[tn].y * 0.25f + b) + ((i0 + 1) == o ? 1.0f : 0.0f);
            v.z = lrelu(acc[tn].z * 0.25f + b) + ((i0 + 2) == o ? 1.0f : 0.0f);
            v.w = lrelu(acc[tn].w * 0.25f + b) + ((i0 + 3) == o ? 1.0f : 0.0f);
            *(f32x4*)(sOut + o * 104 + i0) = v;
        }
    }
    __syncthreads();

    // ---- coalesced store out[t][o][i] ----
    float* __restrict__ outT = out + (size_t)t * 10000u;
    for (int q = tid; q < 2500; q += 512) {
        int o = q / 25, i0 = (q - o * 25) * 4;
        *(float4*)(outT + o * 100 + i0) = *(const float4*)(sOut + o * 104 + i0);
    }
}

extern "C" void kernel_launch(void* const* d_in, const int* in_sizes, int n_in,
                              void* d_out, int out_size, void* d_ws, size_t ws_size,
                              hipStream_t stream) {
    const float* A      = (const float*)d_in[0];
    const float* W      = (const float*)d_in[1];
    const float* attsrc = (const float*)d_in[2];
    const float* attdst = (const float*)d_in[3];
    const float* bias   = (const float*)d_in[4];
    float* outp = (float*)d_out;
    unsigned short* Wp = (unsigned short*)d_ws;   // 4*11648*2 = 93184 B

    const int T = in_sizes[0] / 10000;   // 1024

    prep_w<<<4, 512, 0, stream>>>(W, attsrc, attdst, Wp);

    const int smem_bytes = 47488;
    gat17<<<T, 512, smem_bytes, stream>>>(A, Wp, bias, outp);
}

// Round 19
// 67.891 us; speedup vs baseline: 1.6977x; 1.0036x over previous
//
#include <hip/hip_runtime.h>
#include <hip/hip_bf16.h>

typedef __attribute__((ext_vector_type(8))) short bf16x8;
typedef __attribute__((ext_vector_type(4))) float f32x4;
typedef __attribute__((ext_vector_type(4))) unsigned u32x4;

#define NEG 0.2f
#define CST 104     // bf16 elems per LDS row (208 B stride)
#define HSTRIDE 11648   // 112*104 bf16 elems per head in d_ws

__device__ __forceinline__ float lrelu(float x) { return x >= 0.0f ? x : NEG * x; }

// packed pair via v_cvt_pk_bf16_f32 (RNE)
__device__ __forceinline__ unsigned pk2(float a, float b) {
    __hip_bfloat162 h = __float22bfloat162_rn(float2{a, b});
    unsigned r;
    __builtin_memcpy(&r, &h, sizeof(r));
    return r;
}
__device__ __forceinline__ float bflo(unsigned u) {
    unsigned v = u << 16; float f; __builtin_memcpy(&f, &v, 4); return f;
}
__device__ __forceinline__ float bfhi(unsigned u) {
    unsigned v = u & 0xffff0000u; float f; __builtin_memcpy(&f, &v, 4); return f;
}

// ---- prep (fast): Wp[h] = [112][104] bf16, exact LDS image ----
extern "C" __global__ void prep_w(const float* __restrict__ W,
                                  const float* __restrict__ att_src,
                                  const float* __restrict__ att_dst,
                                  unsigned short* __restrict__ Wp)
{
    __shared__ float red[2][4][128];
    __shared__ float sWS[128], sWD[128];
    const int h = blockIdx.x, tid = threadIdx.x;
    const int f = tid & 127, og = tid >> 7;
    const float* __restrict__ Wh = W + h * 10000;
    float ws = 0.0f, wd = 0.0f;
    if (f < 100) {
        for (int o = og * 25; o < og * 25 + 25; ++o) {
            float wv = Wh[o * 100 + f];
            ws = fmaf(att_src[h * 100 + o], wv, ws);
            wd = fmaf(att_dst[h * 100 + o], wv, wd);
        }
    }
    red[0][og][f] = ws;
    red[1][og][f] = wd;
    __syncthreads();
    if (tid < 256) {
        const int which = tid >> 7, ff = tid & 127;
        float s = (red[which][0][ff] + red[which][1][ff]) +
                  (red[which][2][ff] + red[which][3][ff]);
        (which ? sWD : sWS)[ff] = s;
    }
    __syncthreads();
    unsigned short* __restrict__ D = Wp + h * HSTRIDE;
    for (int q = tid; q < 2912; q += 512) {
        const int o = q / 26, f0 = (q - o * 26) * 4;
        uint2 pp = {0u, 0u};
        if (f0 < 100) {
            if (o < 100) {
                float4 wv = *(const float4*)(Wh + o * 100 + f0);
                pp.x = pk2(wv.x, wv.y);
                pp.y = pk2(wv.z, wv.w);
            } else if (o == 100) {
                pp.x = pk2(sWS[f0], sWS[f0 + 1]);
                pp.y = pk2(sWS[f0 + 2], sWS[f0 + 3]);
            } else if (o == 101) {
                pp.x = pk2(sWD[f0], sWD[f0 + 1]);
                pp.y = pk2(sWD[f0 + 2], sWD[f0 + 3]);
            }
        }
        *(uint2*)(D + o * CST + f0) = pp;
    }
}

// One block per t. 512 threads = 8 waves; waves 0..6 own one 16-row tile each;
// wave 7 does ONLY staging+barriers (its former duplicate compute burned
// shared LDS/MFMA/VALU slots — r18 profile). LDS 47488 B, (512,4) envelope.
// s_setprio(1) around MFMA clusters (T5: 3 independent blocks/CU = phase
// diversity, the m191-positive regime).
extern "C" __global__ void __launch_bounds__(512, 4)
gat18(const float* __restrict__ A, const unsigned short* __restrict__ Wp,
      const float* __restrict__ bias, float* __restrict__ out)
{
    extern __shared__ char smem[];
    unsigned short* P  = (unsigned short*)smem;
    unsigned short* HT = (unsigned short*)(smem + 23296);
    float* sas  = (float*)(smem + 46592);
    float* sad  = (float*)(smem + 47040);
    float* sOut = (float*)smem;

    const int t    = blockIdx.x;
    const int tid  = threadIdx.x;      // 0..511
    const int w    = tid >> 6;         // 0..7
    const int l    = tid & 63;
    const int lr   = l & 15;
    const int lk   = l >> 4;
    const bool HASW = (w < 7);
    const int row  = HASW ? w : 6;
    const int j0   = row * 16 + 4 * lk;        // 0..108
    const bool JW  = HASW && (j0 < 104);
    const float* __restrict__ At = A + (size_t)t * 10000u;
    const f32x4 z4 = {0, 0, 0, 0};

    // ---- init: sas/sad (sas[100..111] = -1e30); zero HT head (64 B guard) ----
    if (tid < 224) {
        float v = (tid >= 100 && tid < 112) ? -1e30f : 0.0f;
        ((float*)(smem + 46592))[tid] = v;
    }
    if (tid >= 224 && tid < 240) ((unsigned*)(smem + 23296))[tid - 224] = 0;

    // ---- xf: direct global loads of X = A_t^T fragments (waves 0..6 only) ----
    const int col = row * 16 + lr;
    const bool cOK = HASW && (col < 100);
    bf16x8 xf[4];
#pragma unroll
    for (int ks = 0; ks < 4; ++ks) {
        const bool kill = (ks == 3) && (lk != 0);
        const int koff = ks * 32 + lk * 8;
        u32x4 uv = {0u, 0u, 0u, 0u};
        if (cOK && !kill) {
#pragma unroll
            for (int jp = 0; jp < 4; ++jp) {
                const int f0 = koff + jp * 2;
                float a0 = (f0     < 100) ? At[f0 * 100 + col]       : 0.0f;
                float a1 = (f0 + 1 < 100) ? At[(f0 + 1) * 100 + col] : 0.0f;
                uv[jp] = pk2(a0, a1);
            }
        }
        xf[ks] = __builtin_bit_cast(bf16x8, uv);
    }
    __syncthreads();   // sas/sad + HT-head init visible

    f32x4 acc[7];
#pragma unroll
    for (int c = 0; c < 7; ++c) acc[c] = z4;

    for (int h = 0; h < 4; ++h) {
        // ---- Wfill: pure 16B copy of prepped head image into P (all waves) ----
        {
            const u32x4* __restrict__ Wg = (const u32x4*)(Wp + h * HSTRIDE);
#pragma unroll
            for (int k = 0; k < 3; ++k) {
                const int q = tid + k * 512;
                if (q < 1456) ((u32x4*)P)[q] = Wg[q];
            }
        }
        __syncthreads();   // (b) W ready; fences prev PV's HT reads

        if (HASW) {
            // ---- GEMM-1, two N-halves; logits free from tile 6 ----
#pragma unroll
            for (int half = 0; half < 2; ++half) {
                const int ntn = half ? 3 : 4;
                f32x4 c[4];
#pragma unroll
                for (int cc = 0; cc < 4; ++cc) c[cc] = z4;
                __builtin_amdgcn_s_setprio(1);
#pragma unroll
                for (int ks = 0; ks < 4; ++ks) {
                    const int koff = ks * 32 + lk * 8;   // A-side zero kills k-pad
                    bf16x8 b[4];
#pragma unroll
                    for (int bb = 0; bb < 4; ++bb)
                        if (bb < ntn)
                            b[bb] = *(const bf16x8*)(P + ((half * 4 + bb) * 16 + lr) * CST + koff);
#pragma unroll
                    for (int bb = 0; bb < 4; ++bb)
                        if (bb < ntn)
                            c[bb] = __builtin_amdgcn_mfma_f32_16x16x32_bf16(xf[ks], b[bb], c[bb], 0, 0, 0);
                }
                __builtin_amdgcn_s_setprio(0);
#pragma unroll
                for (int bb = 0; bb < 4; ++bb)
                    if (bb < ntn) {
                        const int o = (half * 4 + bb) * 16 + lr;
                        if (JW) {
                            uint2 pp;
                            pp.x = pk2(c[bb].x, c[bb].y);
                            pp.y = pk2(c[bb].z, c[bb].w);
                            *(uint2*)(HT + o * CST + j0) = pp;
                        }
                    }
                if (half == 1) {   // tile 6 C-cols 100/101 = a_s, a_d
                    if (lr == 4 && j0 < 100) *(f32x4*)(sas + j0) = c[2];
                    if (lr == 5 && JW)       *(f32x4*)(sad + j0) = c[2];
                }
            }
        }
        __syncthreads();   // (c) HT + sas/sad ready

        if (HASW) {
            // ---- PVprep: per-ks transient exps -> unnorm bf16 af; f32 sum ----
            const float adi = sad[row * 16 + lr];
            float sE = 0.0f;
            bf16x8 af[4];
#pragma unroll
            for (int ks = 0; ks < 4; ++ks) {
                const bool dead = (ks == 3) && (lk != 0);
                const int jb = dead ? 64 : ks * 32 + lk * 8;
                const f32x4 s0 = *(const f32x4*)(sas + jb);
                const f32x4 s1 = *(const f32x4*)(sas + jb + 4);
                float e0 = dead ? 0.0f : __expf(lrelu(adi + s0.x));
                float e1 = dead ? 0.0f : __expf(lrelu(adi + s0.y));
                float e2 = dead ? 0.0f : __expf(lrelu(adi + s0.z));
                float e3 = dead ? 0.0f : __expf(lrelu(adi + s0.w));
                float e4 = dead ? 0.0f : __expf(lrelu(adi + s1.x));
                float e5 = dead ? 0.0f : __expf(lrelu(adi + s1.y));
                float e6 = dead ? 0.0f : __expf(lrelu(adi + s1.z));
                float e7 = dead ? 0.0f : __expf(lrelu(adi + s1.w));
                sE += ((e0 + e1) + (e2 + e3)) + ((e4 + e5) + (e6 + e7));
                u32x4 uv;
                uv.x = pk2(e0, e1); uv.y = pk2(e2, e3);
                uv.z = pk2(e4, e5); uv.w = pk2(e6, e7);
                af[ks] = __builtin_bit_cast(bf16x8, uv);
            }
            sE += __shfl_xor(sE, 16);
            sE += __shfl_xor(sE, 32);
            const float invE = sE > 0.0f ? __builtin_amdgcn_rcpf(sE) : 0.0f;
#pragma unroll
            for (int ks = 0; ks < 4; ++ks) {   // bf16-domain rescale (low pressure)
                u32x4 uv = __builtin_bit_cast(u32x4, af[ks]);
                uv.x = pk2(bflo(uv.x) * invE, bfhi(uv.x) * invE);
                uv.y = pk2(bflo(uv.y) * invE, bfhi(uv.y) * invE);
                uv.z = pk2(bflo(uv.z) * invE, bfhi(uv.z) * invE);
                uv.w = pk2(bflo(uv.w) * invE, bfhi(uv.w) * invE);
                af[ks] = __builtin_bit_cast(bf16x8, uv);
            }

            // ---- PV: acc += alpha * H (direct C accumulation) ----
            __builtin_amdgcn_s_setprio(1);
#pragma unroll
            for (int half = 0; half < 2; ++half) {
                const int ntn = half ? 3 : 4;
#pragma unroll
                for (int ks = 0; ks < 4; ++ks) {
                    const int koff = ks * 32 + lk * 8;
                    bf16x8 b[4];
#pragma unroll
                    for (int bb = 0; bb < 4; ++bb)
                        if (bb < ntn)
                            b[bb] = *(const bf16x8*)(HT + ((half * 4 + bb) * 16 + lr) * CST + koff);
#pragma unroll
                    for (int bb = 0; bb < 4; ++bb)
                        if (bb < ntn)
                            acc[half * 4 + bb] = __builtin_amdgcn_mfma_f32_16x16x32_bf16(
                                af[ks], b[bb], acc[half * 4 + bb], 0, 0, 0);
                }
            }
            __builtin_amdgcn_s_setprio(0);
        }
    }
    __syncthreads();   // all PV done; P+HT dead -> sOut overlay

    // ---- epilogue: sOut[o][i] = lrelu(acc*0.25 + bias[o]) + (i==o) ----
    if (JW) {
        const int i0 = j0;
#pragma unroll
        for (int tn = 0; tn < 7; ++tn) {
            const int o = tn * 16 + lr;
            const float b = (o < 100) ? bias[o] : 0.0f;
            f32x4 v;
            v.x = lrelu(acc[tn].x * 0.25f + b) + ((i0 + 0) == o ? 1.0f : 0.0f);
            v.y = lrelu(acc[tn].y * 0.25f + b) + ((i0 + 1) == o ? 1.0f : 0.0f);
            v.z = lrelu(acc[tn].z * 0.25f + b) + ((i0 + 2) == o ? 1.0f : 0.0f);
            v.w = lrelu(acc[tn].w * 0.25f + b) + ((i0 + 3) == o ? 1.0f : 0.0f);
            *(f32x4*)(sOut + o * 104 + i0) = v;
        }
    }
    __syncthreads();

    // ---- coalesced store out[t][o][i] (all 512 threads) ----
    float* __restrict__ outT = out + (size_t)t * 10000u;
    for (int q = tid; q < 2500; q += 512) {
        int o = q / 25, i0 = (q - o * 25) * 4;
        *(float4*)(outT + o * 100 + i0) = *(const float4*)(sOut + o * 104 + i0);
    }
}

extern "C" void kernel_launch(void* const* d_in, const int* in_sizes, int n_in,
                              void* d_out, int out_size, void* d_ws, size_t ws_size,
                              hipStream_t stream) {
    const float* A      = (const float*)d_in[0];
    const float* W      = (const float*)d_in[1];
    const float* attsrc = (const float*)d_in[2];
    const float* attdst = (const float*)d_in[3];
    const float* bias   = (const float*)d_in[4];
    float* outp = (float*)d_out;
    unsigned short* Wp = (unsigned short*)d_ws;   // 4*11648*2 = 93184 B

    const int T = in_sizes[0] / 10000;   // 1024

    prep_w<<<4, 512, 0, stream>>>(W, attsrc, attdst, Wp);

    const int smem_bytes = 47488;
    gat18<<<T, 512, smem_bytes, stream>>>(A, Wp, bias, outp);
}

// Round 20
// 66.335 us; speedup vs baseline: 1.7375x; 1.0235x over previous
//
#include <hip/hip_runtime.h>
#include <hip/hip_bf16.h>

typedef __attribute__((ext_vector_type(8))) short bf16x8;
typedef __attribute__((ext_vector_type(4))) float f32x4;
typedef __attribute__((ext_vector_type(4))) unsigned u32x4;

#define NEG 0.2f
#define CST 104         // bf16 elems per LDS row (208 B stride)
#define HSTRIDE 11648   // 112*104 bf16 elems per head in d_ws
#define POFF 24192      // P region byte offset in LDS

__device__ __forceinline__ float lrelu(float x) { return x >= 0.0f ? x : NEG * x; }

// packed pair via v_cvt_pk_bf16_f32 (RNE)
__device__ __forceinline__ unsigned pk2(float a, float b) {
    __hip_bfloat162 h = __float22bfloat162_rn(float2{a, b});
    unsigned r;
    __builtin_memcpy(&r, &h, sizeof(r));
    return r;
}
__device__ __forceinline__ float bflo(unsigned u) {
    unsigned v = u << 16; float f; __builtin_memcpy(&f, &v, 4); return f;
}
__device__ __forceinline__ float bfhi(unsigned u) {
    unsigned v = u & 0xffff0000u; float f; __builtin_memcpy(&f, &v, 4); return f;
}

// ---- prep (fast): Wp[h] = [112][104] bf16, exact LDS image ----
extern "C" __global__ void prep_w(const float* __restrict__ W,
                                  const float* __restrict__ att_src,
                                  const float* __restrict__ att_dst,
                                  unsigned short* __restrict__ Wp)
{
    __shared__ float red[2][4][128];
    __shared__ float sWS[128], sWD[128];
    const int h = blockIdx.x, tid = threadIdx.x;
    const int f = tid & 127, og = tid >> 7;
    const float* __restrict__ Wh = W + h * 10000;
    float ws = 0.0f, wd = 0.0f;
    if (f < 100) {
        for (int o = og * 25; o < og * 25 + 25; ++o) {
            float wv = Wh[o * 100 + f];
            ws = fmaf(att_src[h * 100 + o], wv, ws);
            wd = fmaf(att_dst[h * 100 + o], wv, wd);
        }
    }
    red[0][og][f] = ws;
    red[1][og][f] = wd;
    __syncthreads();
    if (tid < 256) {
        const int which = tid >> 7, ff = tid & 127;
        float s = (red[which][0][ff] + red[which][1][ff]) +
                  (red[which][2][ff] + red[which][3][ff]);
        (which ? sWD : sWS)[ff] = s;
    }
    __syncthreads();
    unsigned short* __restrict__ D = Wp + h * HSTRIDE;
    for (int q = tid; q < 2912; q += 512) {
        const int o = q / 26, f0 = (q - o * 26) * 4;
        uint2 pp = {0u, 0u};
        if (f0 < 100) {
            if (o < 100) {
                float4 wv = *(const float4*)(Wh + o * 100 + f0);
                pp.x = pk2(wv.x, wv.y);
                pp.y = pk2(wv.z, wv.w);
            } else if (o == 100) {
                pp.x = pk2(sWS[f0], sWS[f0 + 1]);
                pp.y = pk2(sWS[f0 + 2], sWS[f0 + 3]);
            } else if (o == 101) {
                pp.x = pk2(sWD[f0], sWD[f0 + 1]);
                pp.y = pk2(sWD[f0 + 2], sWD[f0 + 3]);
            }
        }
        *(uint2*)(D + o * CST + f0) = pp;
    }
}

// One block per t. 512 threads = 8 waves; waves 0..6 compute one 16-row tile
// each; wave 7 staging+barriers only. LDS 47744 B -> 3 blocks/CU. (512,4).
// LDS: HT [112][104] bf16 @0; sas[112] @23296, sad[112] @23744 (f32,
//      sas[100..111] = -1e30); P [112][104] bf16 @24192 (+256 B pad).
// ASYNC Wfill: global_load_lds (16 B, zero VGPR dest) issued for head h+1
// right after barrier (c) — P is provably idle from (c) to loop-end barrier,
// whose vmcnt(0) drain lands the data exactly when GEMM-1(h+1) needs it.
// W-load latency+VALU now hidden under PVprep+PV instead of heading each
// iteration. 2 barriers/head, numerics identical to r18/r19.
extern "C" __global__ void __launch_bounds__(512, 4)
gat19(const float* __restrict__ A, const unsigned short* __restrict__ Wp,
      const float* __restrict__ bias, float* __restrict__ out)
{
    extern __shared__ char smem[];
    unsigned short* HT = (unsigned short*)smem;
    float* sas  = (float*)(smem + 23296);
    float* sad  = (float*)(smem + 23744);
    unsigned short* P  = (unsigned short*)(smem + POFF);
    float* sOut = (float*)smem;

    const int t    = blockIdx.x;
    const int tid  = threadIdx.x;      // 0..511
    const int w    = tid >> 6;         // 0..7
    const int l    = tid & 63;
    const int lr   = l & 15;
    const int lk   = l >> 4;
    const bool HASW = (w < 7);
    const int row  = HASW ? w : 6;
    const int j0   = row * 16 + 4 * lk;        // 0..108
    const bool JW  = HASW && (j0 < 104);
    const float* __restrict__ At = A + (size_t)t * 10000u;
    const f32x4 z4 = {0, 0, 0, 0};

    // ---- init stats: sas[0..111] (pads -1e30), sad[0..111] = 0 ----
    if (tid < 224) {
        float v = (tid >= 100 && tid < 112) ? -1e30f : 0.0f;
        ((float*)(smem + 23296))[tid] = v;
    }

    // ---- async Wfill(0): fire-and-forget into P (drained at 1st barrier) ----
    {
        const char* Wg = (const char*)Wp;   // head 0
#pragma unroll
        for (int k = 0; k < 3; ++k) {
            const int c0 = k * 512 + w * 64;
            if (c0 < 1456)
                __builtin_amdgcn_global_load_lds(
                    (const __attribute__((address_space(1))) unsigned*)(Wg + c0 * 16 + l * 16),
                    (__attribute__((address_space(3))) unsigned*)(smem + POFF + c0 * 16),
                    16, 0, 0);
        }
    }

    // ---- xf: direct global loads of X = A_t^T fragments (waves 0..6) ----
    const int col = row * 16 + lr;
    const bool cOK = HASW && (col < 100);
    bf16x8 xf[4];
#pragma unroll
    for (int ks = 0; ks < 4; ++ks) {
        const bool kill = (ks == 3) && (lk != 0);
        const int koff = ks * 32 + lk * 8;
        u32x4 uv = {0u, 0u, 0u, 0u};
        if (cOK && !kill) {
#pragma unroll
            for (int jp = 0; jp < 4; ++jp) {
                const int f0 = koff + jp * 2;
                float a0 = (f0     < 100) ? At[f0 * 100 + col]       : 0.0f;
                float a1 = (f0 + 1 < 100) ? At[(f0 + 1) * 100 + col] : 0.0f;
                uv[jp] = pk2(a0, a1);
            }
        }
        xf[ks] = __builtin_bit_cast(bf16x8, uv);
    }
    __syncthreads();   // (b0): drains Wfill(0) vmcnt; stats visible

    f32x4 acc[7];
#pragma unroll
    for (int c = 0; c < 7; ++c) acc[c] = z4;

    for (int h = 0; h < 4; ++h) {
        if (HASW) {
            // ---- GEMM-1, two N-halves; logits free from tile 6 ----
#pragma unroll
            for (int half = 0; half < 2; ++half) {
                const int ntn = half ? 3 : 4;
                f32x4 c[4];
#pragma unroll
                for (int cc = 0; cc < 4; ++cc) c[cc] = z4;
                __builtin_amdgcn_s_setprio(1);
#pragma unroll
                for (int ks = 0; ks < 4; ++ks) {
                    const int koff = ks * 32 + lk * 8;   // A-side zero kills k-pad
                    bf16x8 b[4];
#pragma unroll
                    for (int bb = 0; bb < 4; ++bb)
                        if (bb < ntn)
                            b[bb] = *(const bf16x8*)(P + ((half * 4 + bb) * 16 + lr) * CST + koff);
#pragma unroll
                    for (int bb = 0; bb < 4; ++bb)
                        if (bb < ntn)
                            c[bb] = __builtin_amdgcn_mfma_f32_16x16x32_bf16(xf[ks], b[bb], c[bb], 0, 0, 0);
                }
                __builtin_amdgcn_s_setprio(0);
#pragma unroll
                for (int bb = 0; bb < 4; ++bb)
                    if (bb < ntn) {
                        const int o = (half * 4 + bb) * 16 + lr;
                        if (JW) {
                            uint2 pp;
                            pp.x = pk2(c[bb].x, c[bb].y);
                            pp.y = pk2(c[bb].z, c[bb].w);
                            *(uint2*)(HT + o * CST + j0) = pp;
                        }
                    }
                if (half == 1) {   // tile 6 C-cols 100/101 = a_s, a_d
                    if (lr == 4 && j0 < 100) *(f32x4*)(sas + j0) = c[2];
                    if (lr == 5 && JW)       *(f32x4*)(sad + j0) = c[2];
                }
            }
        }
        __syncthreads();   // (c) HT + sas/sad ready; P idle from here

        // ---- async Wfill(h+1) into P: latency hides under PVprep+PV ----
        if (h < 3) {
            const char* Wg = (const char*)(Wp + (h + 1) * HSTRIDE);
#pragma unroll
            for (int k = 0; k < 3; ++k) {
                const int c0 = k * 512 + w * 64;
                if (c0 < 1456)
                    __builtin_amdgcn_global_load_lds(
                        (const __attribute__((address_space(1))) unsigned*)(Wg + c0 * 16 + l * 16),
                        (__attribute__((address_space(3))) unsigned*)(smem + POFF + c0 * 16),
                        16, 0, 0);
            }
        }

        if (HASW) {
            // ---- PVprep: per-ks transient exps -> unnorm bf16 af; f32 sum ----
            const float adi = sad[row * 16 + lr];
            float sE = 0.0f;
            bf16x8 af[4];
#pragma unroll
            for (int ks = 0; ks < 4; ++ks) {
                const bool dead = (ks == 3) && (lk != 0);
                const int jb = dead ? 64 : ks * 32 + lk * 8;
                const f32x4 s0 = *(const f32x4*)(sas + jb);
                const f32x4 s1 = *(const f32x4*)(sas + jb + 4);
                float e0 = dead ? 0.0f : __expf(lrelu(adi + s0.x));
                float e1 = dead ? 0.0f : __expf(lrelu(adi + s0.y));
                float e2 = dead ? 0.0f : __expf(lrelu(adi + s0.z));
                float e3 = dead ? 0.0f : __expf(lrelu(adi + s0.w));
                float e4 = dead ? 0.0f : __expf(lrelu(adi + s1.x));
                float e5 = dead ? 0.0f : __expf(lrelu(adi + s1.y));
                float e6 = dead ? 0.0f : __expf(lrelu(adi + s1.z));
                float e7 = dead ? 0.0f : __expf(lrelu(adi + s1.w));
                sE += ((e0 + e1) + (e2 + e3)) + ((e4 + e5) + (e6 + e7));
                u32x4 uv;
                uv.x = pk2(e0, e1); uv.y = pk2(e2, e3);
                uv.z = pk2(e4, e5); uv.w = pk2(e6, e7);
                af[ks] = __builtin_bit_cast(bf16x8, uv);
            }
            sE += __shfl_xor(sE, 16);
            sE += __shfl_xor(sE, 32);
            const float invE = sE > 0.0f ? __builtin_amdgcn_rcpf(sE) : 0.0f;
#pragma unroll
            for (int ks = 0; ks < 4; ++ks) {   // bf16-domain rescale
                u32x4 uv = __builtin_bit_cast(u32x4, af[ks]);
                uv.x = pk2(bflo(uv.x) * invE, bfhi(uv.x) * invE);
                uv.y = pk2(bflo(uv.y) * invE, bfhi(uv.y) * invE);
                uv.z = pk2(bflo(uv.z) * invE, bfhi(uv.z) * invE);
                uv.w = pk2(bflo(uv.w) * invE, bfhi(uv.w) * invE);
                af[ks] = __builtin_bit_cast(bf16x8, uv);
            }

            // ---- PV: acc += alpha * H (direct C accumulation) ----
            __builtin_amdgcn_s_setprio(1);
#pragma unroll
            for (int half = 0; half < 2; ++half) {
                const int ntn = half ? 3 : 4;
#pragma unroll
                for (int ks = 0; ks < 4; ++ks) {
                    const int koff = ks * 32 + lk * 8;
                    bf16x8 b[4];
#pragma unroll
                    for (int bb = 0; bb < 4; ++bb)
                        if (bb < ntn)
                            b[bb] = *(const bf16x8*)(HT + ((half * 4 + bb) * 16 + lr) * CST + koff);
#pragma unroll
                    for (int bb = 0; bb < 4; ++bb)
                        if (bb < ntn)
                            acc[half * 4 + bb] = __builtin_amdgcn_mfma_f32_16x16x32_bf16(
                                af[ks], b[bb], acc[half * 4 + bb], 0, 0, 0);
                }
            }
            __builtin_amdgcn_s_setprio(0);
        }
        __syncthreads();   // (d): drains Wfill(h+1) -> P ready; HT reusable
    }

    // ---- epilogue: sOut[o][i] = lrelu(acc*0.25 + bias[o]) + (i==o) ----
    if (JW) {
        const int i0 = j0;
#pragma unroll
        for (int tn = 0; tn < 7; ++tn) {
            const int o = tn * 16 + lr;
            const float b = (o < 100) ? bias[o] : 0.0f;
            f32x4 v;
            v.x = lrelu(acc[tn].x * 0.25f + b) + ((i0 + 0) == o ? 1.0f : 0.0f);
            v.y = lrelu(acc[tn].y * 0.25f + b) + ((i0 + 1) == o ? 1.0f : 0.0f);
            v.z = lrelu(acc[tn].z * 0.25f + b) + ((i0 + 2) == o ? 1.0f : 0.0f);
            v.w = lrelu(acc[tn].w * 0.25f + b) + ((i0 + 3) == o ? 1.0f : 0.0f);
            *(f32x4*)(sOut + o * 104 + i0) = v;
        }
    }
    __syncthreads();

    // ---- coalesced store out[t][o][i] ----
    float* __restrict__ outT = out + (size_t)t * 10000u;
    for (int q = tid; q < 2500; q += 512) {
        int o = q / 25, i0 = (q - o * 25) * 4;
        *(float4*)(outT + o * 100 + i0) = *(const float4*)(sOut + o * 104 + i0);
    }
}

extern "C" void kernel_launch(void* const* d_in, const int* in_sizes, int n_in,
                              void* d_out, int out_size, void* d_ws, size_t ws_size,
                              hipStream_t stream) {
    const float* A      = (const float*)d_in[0];
    const float* W      = (const float*)d_in[1];
    const float* attsrc = (const float*)d_in[2];
    const float* attdst = (const float*)d_in[3];
    const float* bias   = (const float*)d_in[4];
    float* outp = (float*)d_out;
    unsigned short* Wp = (unsigned short*)d_ws;   // 4*11648*2 = 93184 B

    const int T = in_sizes[0] / 10000;   // 1024

    prep_w<<<4, 512, 0, stream>>>(W, attsrc, attdst, Wp);

    const int smem_bytes = 47744;
    gat19<<<T, 512, smem_bytes, stream>>>(A, Wp, bias, outp);
}